// Round 1
// baseline (693.287 us; speedup 1.0000x reference)
//
#include <hip/hip_runtime.h>

// GCN on MI355X. Pipeline:
//   deg/hist -> dinv -> CSR (scan + fill) -> prop6(x) -> gemm0+relu
//   -> [gemm128 -> aggregate+bias+relu] x2 -> gemm128+leaky x2 -> final dot
// Key trick: layer-0 propagates BEFORE the 6->128 linear (A(XW)=(AX)W),
// cutting layer-0 gather traffic 845MB -> 40MB.

#define HDIM 128

// ---------------- graph preprocessing ----------------

__global__ void init_deg(int* deg, int n) {
  int i = blockIdx.x * blockDim.x + threadIdx.x;
  if (i < n) deg[i] = 1;  // self loop
}

__global__ void hist_kernel(const int* __restrict__ ei, int E, int* __restrict__ deg) {
  int e = blockIdx.x * blockDim.x + threadIdx.x;
  if (e < E) atomicAdd(&deg[ei[E + e]], 1);  // dst = ei[1][e]
}

__global__ void dinv_kernel(const int* __restrict__ deg, float* __restrict__ dinv, int n) {
  int i = blockIdx.x * blockDim.x + threadIdx.x;
  if (i < n) dinv[i] = rsqrtf((float)deg[i]);
}

// Exclusive scan of (deg[i]-1) over n elements, single block of 256 threads,
// 4096 elements per chunk (16 per thread). Writes off[0..n] and cursor copy.
__global__ __launch_bounds__(256) void scan_kernel(const int* __restrict__ deg,
                                                   int* __restrict__ off,
                                                   int* __restrict__ cursor, int n) {
  __shared__ int wsum[4];
  __shared__ int carry_s;
  int tid = threadIdx.x, lane = tid & 63, wid = tid >> 6;
  if (tid == 0) carry_s = 0;
  __syncthreads();
  int nchunks = (n + 4095) / 4096;
  for (int c = 0; c < nchunks; ++c) {
    int base = c * 4096 + tid * 16;
    int v[16];
#pragma unroll
    for (int j = 0; j < 16; ++j) {
      int i = base + j;
      v[j] = (i < n) ? (deg[i] - 1) : 0;
    }
    int s = 0;
#pragma unroll
    for (int j = 0; j < 16; ++j) { int t = v[j]; v[j] = s; s += t; }
    int tot = s;
    int inc = tot;
#pragma unroll
    for (int d = 1; d < 64; d <<= 1) {
      int t = __shfl_up(inc, (unsigned)d, 64);
      if (lane >= d) inc += t;
    }
    if (lane == 63) wsum[wid] = inc;
    int texcl = inc - tot;
    __syncthreads();
    int wexcl = 0, ctot = 0;
#pragma unroll
    for (int w = 0; w < 4; ++w) {
      int ws = wsum[w];
      if (w < wid) wexcl += ws;
      ctot += ws;
    }
    int cbase = carry_s + wexcl + texcl;
#pragma unroll
    for (int j = 0; j < 16; ++j) {
      int i = base + j;
      if (i < n) { off[i] = cbase + v[j]; cursor[i] = cbase + v[j]; }
    }
    __syncthreads();
    if (tid == 0) carry_s += ctot;
    __syncthreads();
  }
  if (tid == 0) off[n] = carry_s;  // == E
}

__global__ void fill_kernel(const int* __restrict__ ei, int E,
                            const float* __restrict__ dinv,
                            int* __restrict__ cursor,
                            int* __restrict__ csr_src, float* __restrict__ csr_w) {
  int e = blockIdx.x * blockDim.x + threadIdx.x;
  if (e >= E) return;
  int s = ei[e], d = ei[E + e];
  int pos = atomicAdd(&cursor[d], 1);
  csr_src[pos] = s;
  csr_w[pos] = dinv[s] * dinv[d];
}

// ---------------- layer 0: propagate 6-dim features ----------------
// 8 lanes per node (6 active). aggx[n][0..5] = dinv^2 * x[n] + sum_e w*x[src]
__global__ void prop6_kernel(const float* __restrict__ x, const int* __restrict__ off,
                             const int* __restrict__ csr_src, const float* __restrict__ csr_w,
                             const float* __restrict__ dinv, float* __restrict__ aggx, int n) {
  int g = (blockIdx.x * blockDim.x + threadIdx.x) >> 3;
  int l = threadIdx.x & 7;
  if (g >= n) return;
  float di = dinv[g];
  float acc = 0.f;
  if (l < 6) acc = di * di * x[g * 6 + l];
  int e0 = off[g], e1 = off[g + 1];
  for (int e = e0; e < e1; ++e) {
    int s = csr_src[e];
    float w = csr_w[e];
    if (l < 6) acc += w * x[s * 6 + l];
  }
  if (l < 6) aggx[g * 6 + l] = acc;
}

// h0 = relu(aggx @ W0 + b0): [n,6]x[6,128]. 2 nodes per 256-block.
__global__ void gemm0_kernel(const float* __restrict__ aggx, const float* __restrict__ W0,
                             const float* __restrict__ b0, float* __restrict__ out, int n) {
  __shared__ float Ws[6 * 128];
  __shared__ float bs[128];
  for (int i = threadIdx.x; i < 6 * 128; i += 256) Ws[i] = W0[i];
  if (threadIdx.x < 128) bs[threadIdx.x] = b0[threadIdx.x];
  __syncthreads();
  int nd = blockIdx.x * 2 + (threadIdx.x >> 7);
  int f = threadIdx.x & 127;
  if (nd >= n) return;
  float acc = bs[f];
#pragma unroll
  for (int k = 0; k < 6; ++k) acc += aggx[nd * 6 + k] * Ws[k * 128 + f];
  out[nd * 128 + f] = fmaxf(acc, 0.f);
}

// ---------------- dense GEMM [n,128] @ [128,128] ----------------
// ACT: 0 = raw (no bias), 2 = bias + leaky_relu(0.01)
template <int ACT>
__global__ __launch_bounds__(256) void gemm128_kernel(const float* __restrict__ in,
                                                      const float* __restrict__ W,
                                                      const float* __restrict__ bias,
                                                      float* __restrict__ out, int n) {
  __shared__ float Ws[64 * 128];   // 32KB: half of W (k-phase)
  __shared__ float inS[32 * 128];  // 16KB: 32-row input tile
  int tid = threadIdx.x;
  int r0 = (tid >> 5) * 4;
  int f0 = (tid & 31) * 4;
  int rowBase = blockIdx.x * 32;
  {
    const float4* src = (const float4*)(in + (size_t)rowBase * HDIM);
    float4* dst = (float4*)inS;
    int nrow = n - rowBase; if (nrow > 32) nrow = 32;
    int nf4 = nrow * 32;
    for (int i = tid; i < 32 * 32; i += 256)
      dst[i] = (i < nf4) ? src[i] : make_float4(0.f, 0.f, 0.f, 0.f);
  }
  float acc[4][4];
#pragma unroll
  for (int i = 0; i < 4; ++i)
#pragma unroll
    for (int j = 0; j < 4; ++j) acc[i][j] = 0.f;

  for (int ph = 0; ph < 2; ++ph) {
    __syncthreads();
    const float4* wsrc = (const float4*)(W + (size_t)ph * 64 * HDIM);
    float4* wdst = (float4*)Ws;
#pragma unroll
    for (int i = 0; i < 8; ++i) wdst[tid + i * 256] = wsrc[tid + i * 256];
    __syncthreads();
#pragma unroll 4
    for (int k = 0; k < 64; ++k) {
      int kk = ph * 64 + k;
      float a0 = inS[(r0 + 0) * HDIM + kk];
      float a1 = inS[(r0 + 1) * HDIM + kk];
      float a2 = inS[(r0 + 2) * HDIM + kk];
      float a3 = inS[(r0 + 3) * HDIM + kk];
      float4 w4 = *(const float4*)&Ws[k * HDIM + f0];
      acc[0][0] += a0 * w4.x; acc[0][1] += a0 * w4.y; acc[0][2] += a0 * w4.z; acc[0][3] += a0 * w4.w;
      acc[1][0] += a1 * w4.x; acc[1][1] += a1 * w4.y; acc[1][2] += a1 * w4.z; acc[1][3] += a1 * w4.w;
      acc[2][0] += a2 * w4.x; acc[2][1] += a2 * w4.y; acc[2][2] += a2 * w4.z; acc[2][3] += a2 * w4.w;
      acc[3][0] += a3 * w4.x; acc[3][1] += a3 * w4.y; acc[3][2] += a3 * w4.z; acc[3][3] += a3 * w4.w;
    }
  }
  float4 bv = make_float4(0.f, 0.f, 0.f, 0.f);
  if (ACT == 2) bv = *(const float4*)&bias[f0];
#pragma unroll
  for (int i = 0; i < 4; ++i) {
    int r = rowBase + r0 + i;
    if (r < n) {
      float4 o;
      o.x = acc[i][0] + bv.x; o.y = acc[i][1] + bv.y;
      o.z = acc[i][2] + bv.z; o.w = acc[i][3] + bv.w;
      if (ACT == 2) {
        o.x = o.x > 0.f ? o.x : 0.01f * o.x;
        o.y = o.y > 0.f ? o.y : 0.01f * o.y;
        o.z = o.z > 0.f ? o.z : 0.01f * o.z;
        o.w = o.w > 0.f ? o.w : 0.01f * o.w;
      }
      *(float4*)&out[(size_t)r * HDIM + f0] = o;
    }
  }
}

// ---------------- aggregation (pull, CSR): one wave per node ----------------
// out[n][f] = relu( sum_e w_e * t[src_e][f] + dinv[n]^2 * t[n][f] + b[f] )
__global__ __launch_bounds__(256) void aggregate_kernel(const float* __restrict__ t,
                                                        const int* __restrict__ off,
                                                        const int* __restrict__ csr_src,
                                                        const float* __restrict__ csr_w,
                                                        const float* __restrict__ dinv,
                                                        const float* __restrict__ bias,
                                                        float* __restrict__ out, int n) {
  int node = (blockIdx.x * blockDim.x + threadIdx.x) >> 6;
  int lane = threadIdx.x & 63;
  if (node >= n) return;
  int f = lane * 2;
  float di = dinv[node];
  float self = di * di;
  float2 v = *(const float2*)&t[(size_t)node * HDIM + f];
  float ax = self * v.x, ay = self * v.y;
  int e0 = off[node], e1 = off[node + 1];
  if (e0 < e1) {
    int s = csr_src[e0];
    float w = csr_w[e0];
    float2 u = *(const float2*)&t[(size_t)s * HDIM + f];
    for (int e = e0 + 1; e < e1; ++e) {
      int s2 = csr_src[e];
      float w2 = csr_w[e];
      float2 u2 = *(const float2*)&t[(size_t)s2 * HDIM + f];
      ax += w * u.x; ay += w * u.y;
      u = u2; w = w2;
    }
    ax += w * u.x; ay += w * u.y;
  }
  float2 b = *(const float2*)&bias[f];
  ax = fmaxf(ax + b.x, 0.f);
  ay = fmaxf(ay + b.y, 0.f);
  float2 o; o.x = ax; o.y = ay;
  *(float2*)&out[(size_t)node * HDIM + f] = o;
}

// ---------------- final: out[n] = h @ Rw2 + Rb2 ----------------
__global__ void final_kernel(const float* __restrict__ h, const float* __restrict__ Rw2,
                             const float* __restrict__ Rb2, float* __restrict__ out, int n) {
  int node = (blockIdx.x * blockDim.x + threadIdx.x) >> 6;
  int lane = threadIdx.x & 63;
  if (node >= n) return;
  float2 v = *(const float2*)&h[(size_t)node * HDIM + lane * 2];
  float2 c = *(const float2*)&Rw2[lane * 2];
  float s = v.x * c.x + v.y * c.y;
#pragma unroll
  for (int d = 32; d > 0; d >>= 1) s += __shfl_down(s, (unsigned)d, 64);
  if (lane == 0) out[node] = s + Rb2[0];
}

// ---------------- host ----------------

static inline size_t align256(size_t x) { return (x + 255) & ~(size_t)255; }

extern "C" void kernel_launch(void* const* d_in, const int* in_sizes, int n_in,
                              void* d_out, int out_size, void* d_ws, size_t ws_size,
                              hipStream_t stream) {
  const float* x   = (const float*)d_in[0];
  const int*   ei  = (const int*)d_in[1];
  const float* W0  = (const float*)d_in[2];
  const float* b0  = (const float*)d_in[3];
  const float* W1  = (const float*)d_in[4];
  const float* b1  = (const float*)d_in[5];
  const float* W2  = (const float*)d_in[6];
  const float* b2  = (const float*)d_in[7];
  const float* Rw0 = (const float*)d_in[8];
  const float* Rb0 = (const float*)d_in[9];
  const float* Rw1 = (const float*)d_in[10];
  const float* Rb1 = (const float*)d_in[11];
  const float* Rw2 = (const float*)d_in[12];
  const float* Rb2 = (const float*)d_in[13];
  float* out = (float*)d_out;

  int N = in_sizes[0] / 6;
  int E = in_sizes[1] / 2;

  char* p = (char*)d_ws;
  size_t o = 0;
  int* deg     = (int*)(p + o); o = align256(o + (size_t)N * 4);
  int* cursor  = (int*)(p + o); o = align256(o + (size_t)N * 4);
  int* off     = (int*)(p + o); o = align256(o + (size_t)(N + 1) * 4);
  float* dinv  = (float*)(p + o); o = align256(o + (size_t)N * 4);
  int* csr_src = (int*)(p + o); o = align256(o + (size_t)E * 4);
  float* csr_w = (float*)(p + o); o = align256(o + (size_t)E * 4);
  float* aggx  = (float*)(p + o); o = align256(o + (size_t)N * 6 * 4);
  float* A     = (float*)(p + o); o = align256(o + (size_t)N * HDIM * 4);
  float* B     = (float*)(p + o); o = align256(o + (size_t)N * HDIM * 4);
  (void)ws_size;

  // graph prep
  init_deg<<<(N + 255) / 256, 256, 0, stream>>>(deg, N);
  hist_kernel<<<(E + 255) / 256, 256, 0, stream>>>(ei, E, deg);
  dinv_kernel<<<(N + 255) / 256, 256, 0, stream>>>(deg, dinv, N);
  scan_kernel<<<1, 256, 0, stream>>>(deg, off, cursor, N);
  fill_kernel<<<(E + 255) / 256, 256, 0, stream>>>(ei, E, dinv, cursor, csr_src, csr_w);

  // layer 0: propagate in 6-dim, then 6->128 gemm + relu
  prop6_kernel<<<(N + 31) / 32, 256, 0, stream>>>(x, off, csr_src, csr_w, dinv, aggx, N);
  gemm0_kernel<<<(N + 1) / 2, 256, 0, stream>>>(aggx, W0, b0, A, N);

  int gemmGrid = (N + 31) / 32;
  int aggGrid = (N + 3) / 4;

  // conv1
  gemm128_kernel<0><<<gemmGrid, 256, 0, stream>>>(A, W1, nullptr, B, N);
  aggregate_kernel<<<aggGrid, 256, 0, stream>>>(B, off, csr_src, csr_w, dinv, b1, A, N);
  // conv2
  gemm128_kernel<0><<<gemmGrid, 256, 0, stream>>>(A, W2, nullptr, B, N);
  aggregate_kernel<<<aggGrid, 256, 0, stream>>>(B, off, csr_src, csr_w, dinv, b2, A, N);
  // MLP head
  gemm128_kernel<2><<<gemmGrid, 256, 0, stream>>>(A, Rw0, Rb0, B, N);
  gemm128_kernel<2><<<gemmGrid, 256, 0, stream>>>(B, Rw1, Rb1, A, N);
  final_kernel<<<(N + 3) / 4, 256, 0, stream>>>(A, Rw2, Rb2, out, N);
}

// Round 5
// 561.676 us; speedup vs baseline: 1.2343x; 1.2343x over previous
//
#include <hip/hip_runtime.h>

// GCN on MI355X. Pipeline:
//   deg/hist -> dinv -> parallel scan (3 kernels) -> fill (int2 records)
//   -> prop6(x) -> gemm0+relu -> [gemm128 -> aggregate+bias+relu] x2
//   -> gemm128+leaky -> gemm128+leaky+fused-final-dot
// R1 changes (re-submitted after infra failures x3): single 8B record per edge
// in fill (halve scatter lines), parallel scan, fused final dot, batched gemm0.

#define HDIM 128

// ---------------- graph preprocessing ----------------

__global__ void init_deg(int* deg, int n) {
  int i = blockIdx.x * blockDim.x + threadIdx.x;
  if (i < n) deg[i] = 1;  // self loop
}

__global__ void hist_kernel(const int* __restrict__ ei, int E, int* __restrict__ deg) {
  int e = blockIdx.x * blockDim.x + threadIdx.x;
  if (e < E) atomicAdd(&deg[ei[E + e]], 1);  // dst = ei[1][e]
}

__global__ void dinv_kernel(const int* __restrict__ deg, float* __restrict__ dinv, int n) {
  int i = blockIdx.x * blockDim.x + threadIdx.x;
  if (i < n) dinv[i] = rsqrtf((float)deg[i]);
}

// --- parallel exclusive scan of (deg[i]-1), 256 elems/block ---

__global__ __launch_bounds__(256) void block_sums_kernel(const int* __restrict__ deg,
                                                         int* __restrict__ bsums, int n) {
  int i = blockIdx.x * 256 + threadIdx.x;
  int v = (i < n) ? (deg[i] - 1) : 0;
#pragma unroll
  for (int d = 1; d < 64; d <<= 1) v += __shfl_xor(v, d, 64);
  __shared__ int ws[4];
  int lane = threadIdx.x & 63, wid = threadIdx.x >> 6;
  if (lane == 0) ws[wid] = v;
  __syncthreads();
  if (threadIdx.x == 0) bsums[blockIdx.x] = ws[0] + ws[1] + ws[2] + ws[3];
}

// one block; nb <= 256
__global__ __launch_bounds__(256) void scan_bsums_kernel(const int* __restrict__ bsums,
                                                         int* __restrict__ bscan, int nb) {
  int tid = threadIdx.x, lane = tid & 63, wid = tid >> 6;
  int v = (tid < nb) ? bsums[tid] : 0;
  int inc = v;
#pragma unroll
  for (int d = 1; d < 64; d <<= 1) {
    int t = __shfl_up(inc, (unsigned)d, 64);
    if (lane >= d) inc += t;
  }
  __shared__ int ws[4];
  if (lane == 63) ws[wid] = inc;
  __syncthreads();
  int woff = 0;
  for (int w = 0; w < wid; ++w) woff += ws[w];
  inc += woff;
  if (tid < nb) bscan[tid] = inc - v;
}

__global__ __launch_bounds__(256) void write_off_kernel(const int* __restrict__ deg,
                                                        const int* __restrict__ bscan,
                                                        int* __restrict__ off,
                                                        int* __restrict__ cursor, int n) {
  int i = blockIdx.x * 256 + threadIdx.x;
  int v = (i < n) ? (deg[i] - 1) : 0;
  int lane = threadIdx.x & 63, wid = threadIdx.x >> 6;
  int inc = v;
#pragma unroll
  for (int d = 1; d < 64; d <<= 1) {
    int t = __shfl_up(inc, (unsigned)d, 64);
    if (lane >= d) inc += t;
  }
  __shared__ int ws[4];
  if (lane == 63) ws[wid] = inc;
  __syncthreads();
  int woff = 0;
  for (int w = 0; w < wid; ++w) woff += ws[w];
  inc += woff;
  int base = bscan[blockIdx.x];
  if (i < n) {
    int ex = base + inc - v;
    off[i] = ex;
    cursor[i] = ex;
    if (i == n - 1) off[n] = base + inc;
  }
}

// one 8B record per edge: {src, bits(w)} — halves scatter-line count vs 2 arrays
__global__ void fill_kernel(const int* __restrict__ ei, int E,
                            const float* __restrict__ dinv,
                            int* __restrict__ cursor, int2* __restrict__ recs) {
  int e = blockIdx.x * blockDim.x + threadIdx.x;
  if (e >= E) return;
  int s = ei[e], d = ei[E + e];
  float w = dinv[s] * dinv[d];
  int pos = atomicAdd(&cursor[d], 1);
  recs[pos] = make_int2(s, __float_as_int(w));
}

// ---------------- layer 0: propagate 6-dim features ----------------
__global__ void prop6_kernel(const float* __restrict__ x, const int* __restrict__ off,
                             const int2* __restrict__ recs,
                             const float* __restrict__ dinv, float* __restrict__ aggx, int n) {
  int g = (blockIdx.x * blockDim.x + threadIdx.x) >> 3;
  int l = threadIdx.x & 7;
  if (g >= n) return;
  float di = dinv[g];
  float acc = 0.f;
  if (l < 6) acc = di * di * x[g * 6 + l];
  int e0 = off[g], e1 = off[g + 1];
  for (int e = e0; e < e1; ++e) {
    int2 r = recs[e];
    float w = __int_as_float(r.y);
    if (l < 6) acc += w * x[r.x * 6 + l];
  }
  if (l < 6) aggx[g * 6 + l] = acc;
}

// h0 = relu(aggx @ W0 + b0): [n,6]x[6,128]. 16 nodes per 256-block.
__global__ __launch_bounds__(256) void gemm0_kernel(const float* __restrict__ aggx,
                                                    const float* __restrict__ W0,
                                                    const float* __restrict__ b0,
                                                    float* __restrict__ out, int n) {
  __shared__ float Ws[6 * 128];
  __shared__ float bs[128];
  for (int i = threadIdx.x; i < 6 * 128; i += 256) Ws[i] = W0[i];
  if (threadIdx.x < 128) bs[threadIdx.x] = b0[threadIdx.x];
  __syncthreads();
  int f = threadIdx.x & 127;
  int h = threadIdx.x >> 7;  // 0 or 1
  int base = blockIdx.x * 16;
#pragma unroll
  for (int j = 0; j < 8; ++j) {
    int nd = base + h * 8 + j;
    if (nd < n) {
      float acc = bs[f];
#pragma unroll
      for (int k = 0; k < 6; ++k) acc += aggx[nd * 6 + k] * Ws[k * 128 + f];
      out[(size_t)nd * HDIM + f] = fmaxf(acc, 0.f);
    }
  }
}

// ---------------- dense GEMM [n,128] @ [128,128] ----------------
// ACT: 0 = raw (no bias), 2 = bias + leaky_relu(0.01),
//      3 = bias + leaky_relu then fused dot with rw2 -> out1[n]
template <int ACT>
__global__ __launch_bounds__(256) void gemm128_kernel(const float* __restrict__ in,
                                                      const float* __restrict__ W,
                                                      const float* __restrict__ bias,
                                                      float* __restrict__ out, int n,
                                                      const float* __restrict__ rw2,
                                                      const float* __restrict__ rb2,
                                                      float* __restrict__ out1) {
  __shared__ float Ws[64 * 128];   // 32KB: half of W (k-phase)
  __shared__ float inS[32 * 128];  // 16KB: 32-row input tile
  int tid = threadIdx.x;
  int r0 = (tid >> 5) * 4;
  int f0 = (tid & 31) * 4;
  int rowBase = blockIdx.x * 32;
  {
    const float4* src = (const float4*)(in + (size_t)rowBase * HDIM);
    float4* dst = (float4*)inS;
    int nrow = n - rowBase; if (nrow > 32) nrow = 32;
    int nf4 = nrow * 32;
    for (int i = tid; i < 32 * 32; i += 256)
      dst[i] = (i < nf4) ? src[i] : make_float4(0.f, 0.f, 0.f, 0.f);
  }
  float acc[4][4];
#pragma unroll
  for (int i = 0; i < 4; ++i)
#pragma unroll
    for (int j = 0; j < 4; ++j) acc[i][j] = 0.f;

  for (int ph = 0; ph < 2; ++ph) {
    __syncthreads();
    const float4* wsrc = (const float4*)(W + (size_t)ph * 64 * HDIM);
    float4* wdst = (float4*)Ws;
#pragma unroll
    for (int i = 0; i < 8; ++i) wdst[tid + i * 256] = wsrc[tid + i * 256];
    __syncthreads();
#pragma unroll 4
    for (int k = 0; k < 64; ++k) {
      int kk = ph * 64 + k;
      float a0 = inS[(r0 + 0) * HDIM + kk];
      float a1 = inS[(r0 + 1) * HDIM + kk];
      float a2 = inS[(r0 + 2) * HDIM + kk];
      float a3 = inS[(r0 + 3) * HDIM + kk];
      float4 w4 = *(const float4*)&Ws[k * HDIM + f0];
      acc[0][0] += a0 * w4.x; acc[0][1] += a0 * w4.y; acc[0][2] += a0 * w4.z; acc[0][3] += a0 * w4.w;
      acc[1][0] += a1 * w4.x; acc[1][1] += a1 * w4.y; acc[1][2] += a1 * w4.z; acc[1][3] += a1 * w4.w;
      acc[2][0] += a2 * w4.x; acc[2][1] += a2 * w4.y; acc[2][2] += a2 * w4.z; acc[2][3] += a2 * w4.w;
      acc[3][0] += a3 * w4.x; acc[3][1] += a3 * w4.y; acc[3][2] += a3 * w4.z; acc[3][3] += a3 * w4.w;
    }
  }
  float4 bv = make_float4(0.f, 0.f, 0.f, 0.f);
  if (ACT >= 2) bv = *(const float4*)&bias[f0];

  if (ACT == 3) {
    float4 w2 = *(const float4*)&rw2[f0];
    float p[4];
#pragma unroll
    for (int i = 0; i < 4; ++i) {
      float ox = acc[i][0] + bv.x, oy = acc[i][1] + bv.y;
      float oz = acc[i][2] + bv.z, ow = acc[i][3] + bv.w;
      ox = ox > 0.f ? ox : 0.01f * ox;
      oy = oy > 0.f ? oy : 0.01f * oy;
      oz = oz > 0.f ? oz : 0.01f * oz;
      ow = ow > 0.f ? ow : 0.01f * ow;
      p[i] = ox * w2.x + oy * w2.y + oz * w2.z + ow * w2.w;
    }
#pragma unroll
    for (int d = 1; d < 32; d <<= 1) {
#pragma unroll
      for (int i = 0; i < 4; ++i) p[i] += __shfl_xor(p[i], d, 32);
    }
    if ((tid & 31) == 0) {
      float rb = rb2[0];
#pragma unroll
      for (int i = 0; i < 4; ++i) {
        int r = rowBase + r0 + i;
        if (r < n) out1[r] = p[i] + rb;
      }
    }
    return;
  }

#pragma unroll
  for (int i = 0; i < 4; ++i) {
    int r = rowBase + r0 + i;
    if (r < n) {
      float4 o;
      o.x = acc[i][0] + bv.x; o.y = acc[i][1] + bv.y;
      o.z = acc[i][2] + bv.z; o.w = acc[i][3] + bv.w;
      if (ACT == 2) {
        o.x = o.x > 0.f ? o.x : 0.01f * o.x;
        o.y = o.y > 0.f ? o.y : 0.01f * o.y;
        o.z = o.z > 0.f ? o.z : 0.01f * o.z;
        o.w = o.w > 0.f ? o.w : 0.01f * o.w;
      }
      *(float4*)&out[(size_t)r * HDIM + f0] = o;
    }
  }
}

// ---------------- aggregation (pull, CSR): one wave per node ----------------
__global__ __launch_bounds__(256) void aggregate_kernel(const float* __restrict__ t,
                                                        const int* __restrict__ off,
                                                        const int2* __restrict__ recs,
                                                        const float* __restrict__ dinv,
                                                        const float* __restrict__ bias,
                                                        float* __restrict__ out, int n) {
  int node = (blockIdx.x * blockDim.x + threadIdx.x) >> 6;
  int lane = threadIdx.x & 63;
  if (node >= n) return;
  int f = lane * 2;
  float di = dinv[node];
  float self = di * di;
  float2 v = *(const float2*)&t[(size_t)node * HDIM + f];
  float ax = self * v.x, ay = self * v.y;
  int e0 = off[node], e1 = off[node + 1];
  if (e0 < e1) {
    int2 r = recs[e0];
    float w = __int_as_float(r.y);
    float2 u = *(const float2*)&t[(size_t)r.x * HDIM + f];
    for (int e = e0 + 1; e < e1; ++e) {
      int2 r2 = recs[e];
      float w2 = __int_as_float(r2.y);
      float2 u2 = *(const float2*)&t[(size_t)r2.x * HDIM + f];
      ax += w * u.x; ay += w * u.y;
      u = u2; w = w2;
    }
    ax += w * u.x; ay += w * u.y;
  }
  float2 b = *(const float2*)&bias[f];
  ax = fmaxf(ax + b.x, 0.f);
  ay = fmaxf(ay + b.y, 0.f);
  float2 o; o.x = ax; o.y = ay;
  *(float2*)&out[(size_t)node * HDIM + f] = o;
}

// ---------------- host ----------------

static inline size_t align256(size_t x) { return (x + 255) & ~(size_t)255; }

extern "C" void kernel_launch(void* const* d_in, const int* in_sizes, int n_in,
                              void* d_out, int out_size, void* d_ws, size_t ws_size,
                              hipStream_t stream) {
  const float* x   = (const float*)d_in[0];
  const int*   ei  = (const int*)d_in[1];
  const float* W0  = (const float*)d_in[2];
  const float* b0  = (const float*)d_in[3];
  const float* W1  = (const float*)d_in[4];
  const float* b1  = (const float*)d_in[5];
  const float* W2  = (const float*)d_in[6];
  const float* b2  = (const float*)d_in[7];
  const float* Rw0 = (const float*)d_in[8];
  const float* Rb0 = (const float*)d_in[9];
  const float* Rw1 = (const float*)d_in[10];
  const float* Rb1 = (const float*)d_in[11];
  const float* Rw2 = (const float*)d_in[12];
  const float* Rb2 = (const float*)d_in[13];
  float* out = (float*)d_out;

  int N = in_sizes[0] / 6;
  int E = in_sizes[1] / 2;
  int NB = (N + 255) / 256;

  char* p = (char*)d_ws;
  size_t o = 0;
  int* deg     = (int*)(p + o); o = align256(o + (size_t)N * 4);
  int* cursor  = (int*)(p + o); o = align256(o + (size_t)N * 4);
  int* off     = (int*)(p + o); o = align256(o + (size_t)(N + 1) * 4);
  float* dinv  = (float*)(p + o); o = align256(o + (size_t)N * 4);
  int* bsums   = (int*)(p + o); o = align256(o + (size_t)NB * 4);
  int* bscan   = (int*)(p + o); o = align256(o + (size_t)NB * 4);
  int2* recs   = (int2*)(p + o); o = align256(o + (size_t)E * 8);
  float* aggx  = (float*)(p + o); o = align256(o + (size_t)N * 6 * 4);
  float* A     = (float*)(p + o); o = align256(o + (size_t)N * HDIM * 4);
  float* B     = (float*)(p + o); o = align256(o + (size_t)N * HDIM * 4);
  (void)ws_size;

  // graph prep
  init_deg<<<(N + 255) / 256, 256, 0, stream>>>(deg, N);
  hist_kernel<<<(E + 255) / 256, 256, 0, stream>>>(ei, E, deg);
  dinv_kernel<<<(N + 255) / 256, 256, 0, stream>>>(deg, dinv, N);
  block_sums_kernel<<<NB, 256, 0, stream>>>(deg, bsums, N);
  scan_bsums_kernel<<<1, 256, 0, stream>>>(bsums, bscan, NB);
  write_off_kernel<<<NB, 256, 0, stream>>>(deg, bscan, off, cursor, N);
  fill_kernel<<<(E + 255) / 256, 256, 0, stream>>>(ei, E, dinv, cursor, recs);

  // layer 0: propagate in 6-dim, then 6->128 gemm + relu
  prop6_kernel<<<(N + 31) / 32, 256, 0, stream>>>(x, off, recs, dinv, aggx, N);
  gemm0_kernel<<<(N + 15) / 16, 256, 0, stream>>>(aggx, W0, b0, A, N);

  int gemmGrid = (N + 31) / 32;
  int aggGrid = (N + 3) / 4;

  // conv1
  gemm128_kernel<0><<<gemmGrid, 256, 0, stream>>>(A, W1, nullptr, B, N, nullptr, nullptr, nullptr);
  aggregate_kernel<<<aggGrid, 256, 0, stream>>>(B, off, recs, dinv, b1, A, N);
  // conv2
  gemm128_kernel<0><<<gemmGrid, 256, 0, stream>>>(A, W2, nullptr, B, N, nullptr, nullptr, nullptr);
  aggregate_kernel<<<aggGrid, 256, 0, stream>>>(B, off, recs, dinv, b2, A, N);
  // MLP head
  gemm128_kernel<2><<<gemmGrid, 256, 0, stream>>>(A, Rw0, Rb0, B, N, nullptr, nullptr, nullptr);
  gemm128_kernel<3><<<gemmGrid, 256, 0, stream>>>(B, Rw1, Rb1, A, N, Rw2, Rb2, out);
}

// Round 6
// 537.333 us; speedup vs baseline: 1.2902x; 1.0453x over previous
//
#include <hip/hip_runtime.h>

// GCN on MI355X. Pipeline:
//   deg/hist -> dinv -> parallel scan (3 kernels) -> fill (int2 records)
//   -> prop6(x) -> gemm0+relu -> [gemm128 -> aggregate+bias+relu] x2
//   -> gemm128+leaky -> gemm128+leaky+fused-final-dot
// R5: aggregate/prop6 gather loops 4-deep software-pipelined (was latency-bound
// at 3.4 TB/s with ~1 row in flight/wave); gemm128 A-reads vectorized to float4.

#define HDIM 128

// ---------------- graph preprocessing ----------------

__global__ void init_deg(int* deg, int n) {
  int i = blockIdx.x * blockDim.x + threadIdx.x;
  if (i < n) deg[i] = 1;  // self loop
}

__global__ void hist_kernel(const int* __restrict__ ei, int E, int* __restrict__ deg) {
  int e = blockIdx.x * blockDim.x + threadIdx.x;
  if (e < E) atomicAdd(&deg[ei[E + e]], 1);  // dst = ei[1][e]
}

__global__ void dinv_kernel(const int* __restrict__ deg, float* __restrict__ dinv, int n) {
  int i = blockIdx.x * blockDim.x + threadIdx.x;
  if (i < n) dinv[i] = rsqrtf((float)deg[i]);
}

// --- parallel exclusive scan of (deg[i]-1), 256 elems/block ---

__global__ __launch_bounds__(256) void block_sums_kernel(const int* __restrict__ deg,
                                                         int* __restrict__ bsums, int n) {
  int i = blockIdx.x * 256 + threadIdx.x;
  int v = (i < n) ? (deg[i] - 1) : 0;
#pragma unroll
  for (int d = 1; d < 64; d <<= 1) v += __shfl_xor(v, d, 64);
  __shared__ int ws[4];
  int lane = threadIdx.x & 63, wid = threadIdx.x >> 6;
  if (lane == 0) ws[wid] = v;
  __syncthreads();
  if (threadIdx.x == 0) bsums[blockIdx.x] = ws[0] + ws[1] + ws[2] + ws[3];
}

// one block; nb <= 256
__global__ __launch_bounds__(256) void scan_bsums_kernel(const int* __restrict__ bsums,
                                                         int* __restrict__ bscan, int nb) {
  int tid = threadIdx.x, lane = tid & 63, wid = tid >> 6;
  int v = (tid < nb) ? bsums[tid] : 0;
  int inc = v;
#pragma unroll
  for (int d = 1; d < 64; d <<= 1) {
    int t = __shfl_up(inc, (unsigned)d, 64);
    if (lane >= d) inc += t;
  }
  __shared__ int ws[4];
  if (lane == 63) ws[wid] = inc;
  __syncthreads();
  int woff = 0;
  for (int w = 0; w < wid; ++w) woff += ws[w];
  inc += woff;
  if (tid < nb) bscan[tid] = inc - v;
}

__global__ __launch_bounds__(256) void write_off_kernel(const int* __restrict__ deg,
                                                        const int* __restrict__ bscan,
                                                        int* __restrict__ off,
                                                        int* __restrict__ cursor, int n) {
  int i = blockIdx.x * 256 + threadIdx.x;
  int v = (i < n) ? (deg[i] - 1) : 0;
  int lane = threadIdx.x & 63, wid = threadIdx.x >> 6;
  int inc = v;
#pragma unroll
  for (int d = 1; d < 64; d <<= 1) {
    int t = __shfl_up(inc, (unsigned)d, 64);
    if (lane >= d) inc += t;
  }
  __shared__ int ws[4];
  if (lane == 63) ws[wid] = inc;
  __syncthreads();
  int woff = 0;
  for (int w = 0; w < wid; ++w) woff += ws[w];
  inc += woff;
  int base = bscan[blockIdx.x];
  if (i < n) {
    int ex = base + inc - v;
    off[i] = ex;
    cursor[i] = ex;
    if (i == n - 1) off[n] = base + inc;
  }
}

// one 8B record per edge: {src, bits(w)}
__global__ void fill_kernel(const int* __restrict__ ei, int E,
                            const float* __restrict__ dinv,
                            int* __restrict__ cursor, int2* __restrict__ recs) {
  int e = blockIdx.x * blockDim.x + threadIdx.x;
  if (e >= E) return;
  int s = ei[e], d = ei[E + e];
  float w = dinv[s] * dinv[d];
  int pos = atomicAdd(&cursor[d], 1);
  recs[pos] = make_int2(s, __float_as_int(w));
}

// ---------------- layer 0: propagate 6-dim features ----------------
// 8 lanes per node (6 active); 4-deep pipelined edge loop.
__global__ void prop6_kernel(const float* __restrict__ x, const int* __restrict__ off,
                             const int2* __restrict__ recs,
                             const float* __restrict__ dinv, float* __restrict__ aggx, int n) {
  int g = (blockIdx.x * blockDim.x + threadIdx.x) >> 3;
  int l = threadIdx.x & 7;
  if (g >= n) return;
  float di = dinv[g];
  float acc = 0.f;
  if (l < 6) acc = di * di * x[g * 6 + l];
  int e0 = off[g], e1 = off[g + 1];
  int e = e0;
  for (; e + 4 <= e1; e += 4) {
    int2 r0 = recs[e], r1 = recs[e + 1], r2 = recs[e + 2], r3 = recs[e + 3];
    float u0 = 0.f, u1 = 0.f, u2 = 0.f, u3 = 0.f;
    if (l < 6) {
      u0 = x[r0.x * 6 + l];
      u1 = x[r1.x * 6 + l];
      u2 = x[r2.x * 6 + l];
      u3 = x[r3.x * 6 + l];
    }
    acc += __int_as_float(r0.y) * u0 + __int_as_float(r1.y) * u1 +
           __int_as_float(r2.y) * u2 + __int_as_float(r3.y) * u3;
  }
  for (; e < e1; ++e) {
    int2 r = recs[e];
    if (l < 6) acc += __int_as_float(r.y) * x[r.x * 6 + l];
  }
  if (l < 6) aggx[g * 6 + l] = acc;
}

// h0 = relu(aggx @ W0 + b0): [n,6]x[6,128]. 16 nodes per 256-block.
__global__ __launch_bounds__(256) void gemm0_kernel(const float* __restrict__ aggx,
                                                    const float* __restrict__ W0,
                                                    const float* __restrict__ b0,
                                                    float* __restrict__ out, int n) {
  __shared__ float Ws[6 * 128];
  __shared__ float bs[128];
  for (int i = threadIdx.x; i < 6 * 128; i += 256) Ws[i] = W0[i];
  if (threadIdx.x < 128) bs[threadIdx.x] = b0[threadIdx.x];
  __syncthreads();
  int f = threadIdx.x & 127;
  int h = threadIdx.x >> 7;  // 0 or 1
  int base = blockIdx.x * 16;
#pragma unroll
  for (int j = 0; j < 8; ++j) {
    int nd = base + h * 8 + j;
    if (nd < n) {
      float acc = bs[f];
#pragma unroll
      for (int k = 0; k < 6; ++k) acc += aggx[nd * 6 + k] * Ws[k * 128 + f];
      out[(size_t)nd * HDIM + f] = fmaxf(acc, 0.f);
    }
  }
}

// ---------------- dense GEMM [n,128] @ [128,128] ----------------
// ACT: 0 = raw (no bias), 2 = bias + leaky_relu(0.01),
//      3 = bias + leaky_relu then fused dot with rw2 -> out1[n]
// R5: A-reads vectorized (float4 per row per k-quad; broadcast within wave).
template <int ACT>
__global__ __launch_bounds__(256) void gemm128_kernel(const float* __restrict__ in,
                                                      const float* __restrict__ W,
                                                      const float* __restrict__ bias,
                                                      float* __restrict__ out, int n,
                                                      const float* __restrict__ rw2,
                                                      const float* __restrict__ rb2,
                                                      float* __restrict__ out1) {
  __shared__ float Ws[64 * 128];   // 32KB: half of W (k-phase)
  __shared__ float inS[32 * 128];  // 16KB: 32-row input tile
  int tid = threadIdx.x;
  int r0 = (tid >> 5) * 4;
  int f0 = (tid & 31) * 4;
  int rowBase = blockIdx.x * 32;
  {
    const float4* src = (const float4*)(in + (size_t)rowBase * HDIM);
    float4* dst = (float4*)inS;
    int nrow = n - rowBase; if (nrow > 32) nrow = 32;
    int nf4 = nrow * 32;
    for (int i = tid; i < 32 * 32; i += 256)
      dst[i] = (i < nf4) ? src[i] : make_float4(0.f, 0.f, 0.f, 0.f);
  }
  float acc[4][4];
#pragma unroll
  for (int i = 0; i < 4; ++i)
#pragma unroll
    for (int j = 0; j < 4; ++j) acc[i][j] = 0.f;

  for (int ph = 0; ph < 2; ++ph) {
    __syncthreads();
    const float4* wsrc = (const float4*)(W + (size_t)ph * 64 * HDIM);
    float4* wdst = (float4*)Ws;
#pragma unroll
    for (int i = 0; i < 8; ++i) wdst[tid + i * 256] = wsrc[tid + i * 256];
    __syncthreads();
#pragma unroll 4
    for (int k4 = 0; k4 < 16; ++k4) {
      int kk = ph * 64 + k4 * 4;
      float4 a4[4];
#pragma unroll
      for (int i = 0; i < 4; ++i)
        a4[i] = *(const float4*)&inS[(r0 + i) * HDIM + kk];
#pragma unroll
      for (int q = 0; q < 4; ++q) {
        float4 w4 = *(const float4*)&Ws[(k4 * 4 + q) * HDIM + f0];
#pragma unroll
        for (int i = 0; i < 4; ++i) {
          float a = (q == 0) ? a4[i].x : (q == 1) ? a4[i].y : (q == 2) ? a4[i].z : a4[i].w;
          acc[i][0] += a * w4.x; acc[i][1] += a * w4.y;
          acc[i][2] += a * w4.z; acc[i][3] += a * w4.w;
        }
      }
    }
  }
  float4 bv = make_float4(0.f, 0.f, 0.f, 0.f);
  if (ACT >= 2) bv = *(const float4*)&bias[f0];

  if (ACT == 3) {
    float4 w2 = *(const float4*)&rw2[f0];
    float p[4];
#pragma unroll
    for (int i = 0; i < 4; ++i) {
      float ox = acc[i][0] + bv.x, oy = acc[i][1] + bv.y;
      float oz = acc[i][2] + bv.z, ow = acc[i][3] + bv.w;
      ox = ox > 0.f ? ox : 0.01f * ox;
      oy = oy > 0.f ? oy : 0.01f * oy;
      oz = oz > 0.f ? oz : 0.01f * oz;
      ow = ow > 0.f ? ow : 0.01f * ow;
      p[i] = ox * w2.x + oy * w2.y + oz * w2.z + ow * w2.w;
    }
#pragma unroll
    for (int d = 1; d < 32; d <<= 1) {
#pragma unroll
      for (int i = 0; i < 4; ++i) p[i] += __shfl_xor(p[i], d, 32);
    }
    if ((tid & 31) == 0) {
      float rb = rb2[0];
#pragma unroll
      for (int i = 0; i < 4; ++i) {
        int r = rowBase + r0 + i;
        if (r < n) out1[r] = p[i] + rb;
      }
    }
    return;
  }

#pragma unroll
  for (int i = 0; i < 4; ++i) {
    int r = rowBase + r0 + i;
    if (r < n) {
      float4 o;
      o.x = acc[i][0] + bv.x; o.y = acc[i][1] + bv.y;
      o.z = acc[i][2] + bv.z; o.w = acc[i][3] + bv.w;
      if (ACT == 2) {
        o.x = o.x > 0.f ? o.x : 0.01f * o.x;
        o.y = o.y > 0.f ? o.y : 0.01f * o.y;
        o.z = o.z > 0.f ? o.z : 0.01f * o.z;
        o.w = o.w > 0.f ? o.w : 0.01f * o.w;
      }
      *(float4*)&out[(size_t)r * HDIM + f0] = o;
    }
  }
}

// ---------------- aggregation (pull, CSR): one wave per node ----------------
// R5: 4-deep software pipeline — 4 independent row gathers in flight per wave.
__global__ __launch_bounds__(256) void aggregate_kernel(const float* __restrict__ t,
                                                        const int* __restrict__ off,
                                                        const int2* __restrict__ recs,
                                                        const float* __restrict__ dinv,
                                                        const float* __restrict__ bias,
                                                        float* __restrict__ out, int n) {
  int node = (blockIdx.x * blockDim.x + threadIdx.x) >> 6;
  int lane = threadIdx.x & 63;
  if (node >= n) return;
  const float2* tf = (const float2*)t + lane;  // row r at tf[r*64]
  float di = dinv[node];
  float self = di * di;
  float2 v = tf[(size_t)node * 64];
  float ax = self * v.x, ay = self * v.y;
  int e0 = off[node], e1 = off[node + 1];
  int e = e0;
  for (; e + 4 <= e1; e += 4) {
    int2 r0 = recs[e], r1 = recs[e + 1], r2 = recs[e + 2], r3 = recs[e + 3];
    float2 u0 = tf[(size_t)r0.x * 64];
    float2 u1 = tf[(size_t)r1.x * 64];
    float2 u2 = tf[(size_t)r2.x * 64];
    float2 u3 = tf[(size_t)r3.x * 64];
    float w0 = __int_as_float(r0.y), w1 = __int_as_float(r1.y);
    float w2 = __int_as_float(r2.y), w3 = __int_as_float(r3.y);
    ax += w0 * u0.x; ay += w0 * u0.y;
    ax += w1 * u1.x; ay += w1 * u1.y;
    ax += w2 * u2.x; ay += w2 * u2.y;
    ax += w3 * u3.x; ay += w3 * u3.y;
  }
  for (; e < e1; ++e) {
    int2 r = recs[e];
    float w = __int_as_float(r.y);
    float2 u = tf[(size_t)r.x * 64];
    ax += w * u.x; ay += w * u.y;
  }
  const float2* bf = (const float2*)bias + lane;
  float2 b = *bf;
  ax = fmaxf(ax + b.x, 0.f);
  ay = fmaxf(ay + b.y, 0.f);
  float2 o; o.x = ax; o.y = ay;
  *((float2*)out + (size_t)node * 64 + lane) = o;
}

// ---------------- host ----------------

static inline size_t align256(size_t x) { return (x + 255) & ~(size_t)255; }

extern "C" void kernel_launch(void* const* d_in, const int* in_sizes, int n_in,
                              void* d_out, int out_size, void* d_ws, size_t ws_size,
                              hipStream_t stream) {
  const float* x   = (const float*)d_in[0];
  const int*   ei  = (const int*)d_in[1];
  const float* W0  = (const float*)d_in[2];
  const float* b0  = (const float*)d_in[3];
  const float* W1  = (const float*)d_in[4];
  const float* b1  = (const float*)d_in[5];
  const float* W2  = (const float*)d_in[6];
  const float* b2  = (const float*)d_in[7];
  const float* Rw0 = (const float*)d_in[8];
  const float* Rb0 = (const float*)d_in[9];
  const float* Rw1 = (const float*)d_in[10];
  const float* Rb1 = (const float*)d_in[11];
  const float* Rw2 = (const float*)d_in[12];
  const float* Rb2 = (const float*)d_in[13];
  float* out = (float*)d_out;

  int N = in_sizes[0] / 6;
  int E = in_sizes[1] / 2;
  int NB = (N + 255) / 256;

  char* p = (char*)d_ws;
  size_t o = 0;
  int* deg     = (int*)(p + o); o = align256(o + (size_t)N * 4);
  int* cursor  = (int*)(p + o); o = align256(o + (size_t)N * 4);
  int* off     = (int*)(p + o); o = align256(o + (size_t)(N + 1) * 4);
  float* dinv  = (float*)(p + o); o = align256(o + (size_t)N * 4);
  int* bsums   = (int*)(p + o); o = align256(o + (size_t)NB * 4);
  int* bscan   = (int*)(p + o); o = align256(o + (size_t)NB * 4);
  int2* recs   = (int2*)(p + o); o = align256(o + (size_t)E * 8);
  float* aggx  = (float*)(p + o); o = align256(o + (size_t)N * 6 * 4);
  float* A     = (float*)(p + o); o = align256(o + (size_t)N * HDIM * 4);
  float* B     = (float*)(p + o); o = align256(o + (size_t)N * HDIM * 4);
  (void)ws_size;

  // graph prep
  init_deg<<<(N + 255) / 256, 256, 0, stream>>>(deg, N);
  hist_kernel<<<(E + 255) / 256, 256, 0, stream>>>(ei, E, deg);
  dinv_kernel<<<(N + 255) / 256, 256, 0, stream>>>(deg, dinv, N);
  block_sums_kernel<<<NB, 256, 0, stream>>>(deg, bsums, N);
  scan_bsums_kernel<<<1, 256, 0, stream>>>(bsums, bscan, NB);
  write_off_kernel<<<NB, 256, 0, stream>>>(deg, bscan, off, cursor, N);
  fill_kernel<<<(E + 255) / 256, 256, 0, stream>>>(ei, E, dinv, cursor, recs);

  // layer 0: propagate in 6-dim, then 6->128 gemm + relu
  prop6_kernel<<<(N + 31) / 32, 256, 0, stream>>>(x, off, recs, dinv, aggx, N);
  gemm0_kernel<<<(N + 15) / 16, 256, 0, stream>>>(aggx, W0, b0, A, N);

  int gemmGrid = (N + 31) / 32;
  int aggGrid = (N + 3) / 4;

  // conv1
  gemm128_kernel<0><<<gemmGrid, 256, 0, stream>>>(A, W1, nullptr, B, N, nullptr, nullptr, nullptr);
  aggregate_kernel<<<aggGrid, 256, 0, stream>>>(B, off, recs, dinv, b1, A, N);
  // conv2
  gemm128_kernel<0><<<gemmGrid, 256, 0, stream>>>(A, W2, nullptr, B, N, nullptr, nullptr, nullptr);
  aggregate_kernel<<<aggGrid, 256, 0, stream>>>(B, off, recs, dinv, b2, A, N);
  // MLP head
  gemm128_kernel<2><<<gemmGrid, 256, 0, stream>>>(A, Rw0, Rb0, B, N, nullptr, nullptr, nullptr);
  gemm128_kernel<3><<<gemmGrid, 256, 0, stream>>>(B, Rw1, Rb1, A, N, Rw2, Rb2, out);
}

// Round 8
// 447.915 us; speedup vs baseline: 1.5478x; 1.1996x over previous
//
#include <hip/hip_runtime.h>

// GCN on MI355X. Pipeline:
//   deg/hist -> dinv -> parallel scan -> fill (int2 records)
//   -> prop6(x) -> gemm0+relu -> [gemm128->bf16 -> aggregate(bf16 gather)] x2
//   -> gemm128+leaky -> gemm128+leaky+fused-final-dot
// R6 (resubmitted after infra failure): message tables stored as bf16 ->
// gather rows 512->256B. Aggregate is at the random-gather L2-miss ceiling
// (~3.7 TB/s); halving bytes is the lever. Accumulation stays fp32.

#define HDIM 128

__device__ inline unsigned short bf16rn(float f) {
  unsigned u = __float_as_uint(f);
  unsigned r = (u + 0x7FFFu + ((u >> 16) & 1u)) >> 16;
  return (unsigned short)r;
}
__device__ inline float bf16tof(unsigned short h) {
  return __uint_as_float(((unsigned)h) << 16);
}

// ---------------- graph preprocessing ----------------

__global__ void init_deg(int* deg, int n) {
  int i = blockIdx.x * blockDim.x + threadIdx.x;
  if (i < n) deg[i] = 1;  // self loop
}

__global__ void hist_kernel(const int* __restrict__ ei, int E, int* __restrict__ deg) {
  int e = blockIdx.x * blockDim.x + threadIdx.x;
  if (e < E) atomicAdd(&deg[ei[E + e]], 1);  // dst = ei[1][e]
}

__global__ void dinv_kernel(const int* __restrict__ deg, float* __restrict__ dinv, int n) {
  int i = blockIdx.x * blockDim.x + threadIdx.x;
  if (i < n) dinv[i] = rsqrtf((float)deg[i]);
}

// --- parallel exclusive scan of (deg[i]-1), 256 elems/block ---

__global__ __launch_bounds__(256) void block_sums_kernel(const int* __restrict__ deg,
                                                         int* __restrict__ bsums, int n) {
  int i = blockIdx.x * 256 + threadIdx.x;
  int v = (i < n) ? (deg[i] - 1) : 0;
#pragma unroll
  for (int d = 1; d < 64; d <<= 1) v += __shfl_xor(v, d, 64);
  __shared__ int ws[4];
  int lane = threadIdx.x & 63, wid = threadIdx.x >> 6;
  if (lane == 0) ws[wid] = v;
  __syncthreads();
  if (threadIdx.x == 0) bsums[blockIdx.x] = ws[0] + ws[1] + ws[2] + ws[3];
}

// one block; nb <= 256
__global__ __launch_bounds__(256) void scan_bsums_kernel(const int* __restrict__ bsums,
                                                         int* __restrict__ bscan, int nb) {
  int tid = threadIdx.x, lane = tid & 63, wid = tid >> 6;
  int v = (tid < nb) ? bsums[tid] : 0;
  int inc = v;
#pragma unroll
  for (int d = 1; d < 64; d <<= 1) {
    int t = __shfl_up(inc, (unsigned)d, 64);
    if (lane >= d) inc += t;
  }
  __shared__ int ws[4];
  if (lane == 63) ws[wid] = inc;
  __syncthreads();
  int woff = 0;
  for (int w = 0; w < wid; ++w) woff += ws[w];
  inc += woff;
  if (tid < nb) bscan[tid] = inc - v;
}

__global__ __launch_bounds__(256) void write_off_kernel(const int* __restrict__ deg,
                                                        const int* __restrict__ bscan,
                                                        int* __restrict__ off,
                                                        int* __restrict__ cursor, int n) {
  int i = blockIdx.x * 256 + threadIdx.x;
  int v = (i < n) ? (deg[i] - 1) : 0;
  int lane = threadIdx.x & 63, wid = threadIdx.x >> 6;
  int inc = v;
#pragma unroll
  for (int d = 1; d < 64; d <<= 1) {
    int t = __shfl_up(inc, (unsigned)d, 64);
    if (lane >= d) inc += t;
  }
  __shared__ int ws[4];
  if (lane == 63) ws[wid] = inc;
  __syncthreads();
  int woff = 0;
  for (int w = 0; w < wid; ++w) woff += ws[w];
  inc += woff;
  int base = bscan[blockIdx.x];
  if (i < n) {
    int ex = base + inc - v;
    off[i] = ex;
    cursor[i] = ex;
    if (i == n - 1) off[n] = base + inc;
  }
}

// one 8B record per edge: {src, bits(w)}
__global__ void fill_kernel(const int* __restrict__ ei, int E,
                            const float* __restrict__ dinv,
                            int* __restrict__ cursor, int2* __restrict__ recs) {
  int e = blockIdx.x * blockDim.x + threadIdx.x;
  if (e >= E) return;
  int s = ei[e], d = ei[E + e];
  float w = dinv[s] * dinv[d];
  int pos = atomicAdd(&cursor[d], 1);
  recs[pos] = make_int2(s, __float_as_int(w));
}

// ---------------- layer 0: propagate 6-dim features ----------------
__global__ void prop6_kernel(const float* __restrict__ x, const int* __restrict__ off,
                             const int2* __restrict__ recs,
                             const float* __restrict__ dinv, float* __restrict__ aggx, int n) {
  int g = (blockIdx.x * blockDim.x + threadIdx.x) >> 3;
  int l = threadIdx.x & 7;
  if (g >= n) return;
  float di = dinv[g];
  float acc = 0.f;
  if (l < 6) acc = di * di * x[g * 6 + l];
  int e0 = off[g], e1 = off[g + 1];
  int e = e0;
  for (; e + 4 <= e1; e += 4) {
    int2 r0 = recs[e], r1 = recs[e + 1], r2 = recs[e + 2], r3 = recs[e + 3];
    float u0 = 0.f, u1 = 0.f, u2 = 0.f, u3 = 0.f;
    if (l < 6) {
      u0 = x[r0.x * 6 + l];
      u1 = x[r1.x * 6 + l];
      u2 = x[r2.x * 6 + l];
      u3 = x[r3.x * 6 + l];
    }
    acc += __int_as_float(r0.y) * u0 + __int_as_float(r1.y) * u1 +
           __int_as_float(r2.y) * u2 + __int_as_float(r3.y) * u3;
  }
  for (; e < e1; ++e) {
    int2 r = recs[e];
    if (l < 6) acc += __int_as_float(r.y) * x[r.x * 6 + l];
  }
  if (l < 6) aggx[g * 6 + l] = acc;
}

// h0 = relu(aggx @ W0 + b0): [n,6]x[6,128]. 16 nodes per 256-block.
__global__ __launch_bounds__(256) void gemm0_kernel(const float* __restrict__ aggx,
                                                    const float* __restrict__ W0,
                                                    const float* __restrict__ b0,
                                                    float* __restrict__ out, int n) {
  __shared__ float Ws[6 * 128];
  __shared__ float bs[128];
  for (int i = threadIdx.x; i < 6 * 128; i += 256) Ws[i] = W0[i];
  if (threadIdx.x < 128) bs[threadIdx.x] = b0[threadIdx.x];
  __syncthreads();
  int f = threadIdx.x & 127;
  int h = threadIdx.x >> 7;  // 0 or 1
  int base = blockIdx.x * 16;
#pragma unroll
  for (int j = 0; j < 8; ++j) {
    int nd = base + h * 8 + j;
    if (nd < n) {
      float acc = bs[f];
#pragma unroll
      for (int k = 0; k < 6; ++k) acc += aggx[nd * 6 + k] * Ws[k * 128 + f];
      out[(size_t)nd * HDIM + f] = fmaxf(acc, 0.f);
    }
  }
}

// ---------------- dense GEMM [n,128] @ [128,128] ----------------
// ACT: 0 = raw, no bias, bf16 output (message table for aggregate)
//      2 = bias + leaky_relu(0.01), fp32 output
//      3 = bias + leaky_relu then fused dot with rw2 -> out1[n]
template <int ACT>
__global__ __launch_bounds__(256) void gemm128_kernel(const float* __restrict__ in,
                                                      const float* __restrict__ W,
                                                      const float* __restrict__ bias,
                                                      float* __restrict__ out, int n,
                                                      const float* __restrict__ rw2,
                                                      const float* __restrict__ rb2,
                                                      float* __restrict__ out1) {
  __shared__ float Ws[64 * 128];   // 32KB: half of W (k-phase)
  __shared__ float inS[32 * 128];  // 16KB: 32-row input tile
  int tid = threadIdx.x;
  int r0 = (tid >> 5) * 4;
  int f0 = (tid & 31) * 4;
  int rowBase = blockIdx.x * 32;
  {
    const float4* src = (const float4*)(in + (size_t)rowBase * HDIM);
    float4* dst = (float4*)inS;
    int nrow = n - rowBase; if (nrow > 32) nrow = 32;
    int nf4 = nrow * 32;
    for (int i = tid; i < 32 * 32; i += 256)
      dst[i] = (i < nf4) ? src[i] : make_float4(0.f, 0.f, 0.f, 0.f);
  }
  float acc[4][4];
#pragma unroll
  for (int i = 0; i < 4; ++i)
#pragma unroll
    for (int j = 0; j < 4; ++j) acc[i][j] = 0.f;

  for (int ph = 0; ph < 2; ++ph) {
    __syncthreads();
    const float4* wsrc = (const float4*)(W + (size_t)ph * 64 * HDIM);
    float4* wdst = (float4*)Ws;
#pragma unroll
    for (int i = 0; i < 8; ++i) wdst[tid + i * 256] = wsrc[tid + i * 256];
    __syncthreads();
#pragma unroll 4
    for (int k4 = 0; k4 < 16; ++k4) {
      int kk = ph * 64 + k4 * 4;
      float4 a4[4];
#pragma unroll
      for (int i = 0; i < 4; ++i)
        a4[i] = *(const float4*)&inS[(r0 + i) * HDIM + kk];
#pragma unroll
      for (int q = 0; q < 4; ++q) {
        float4 w4 = *(const float4*)&Ws[(k4 * 4 + q) * HDIM + f0];
#pragma unroll
        for (int i = 0; i < 4; ++i) {
          float a = (q == 0) ? a4[i].x : (q == 1) ? a4[i].y : (q == 2) ? a4[i].z : a4[i].w;
          acc[i][0] += a * w4.x; acc[i][1] += a * w4.y;
          acc[i][2] += a * w4.z; acc[i][3] += a * w4.w;
        }
      }
    }
  }

  if (ACT == 0) {
    // bf16 message table output (8B ushort4 per thread-row)
    unsigned short* ob = (unsigned short*)out;
#pragma unroll
    for (int i = 0; i < 4; ++i) {
      int r = rowBase + r0 + i;
      if (r < n) {
        ushort4 o;
        o.x = bf16rn(acc[i][0]); o.y = bf16rn(acc[i][1]);
        o.z = bf16rn(acc[i][2]); o.w = bf16rn(acc[i][3]);
        *(ushort4*)&ob[(size_t)r * HDIM + f0] = o;
      }
    }
    return;
  }

  float4 bv = *(const float4*)&bias[f0];

  if (ACT == 3) {
    float4 w2 = *(const float4*)&rw2[f0];
    float p[4];
#pragma unroll
    for (int i = 0; i < 4; ++i) {
      float ox = acc[i][0] + bv.x, oy = acc[i][1] + bv.y;
      float oz = acc[i][2] + bv.z, ow = acc[i][3] + bv.w;
      ox = ox > 0.f ? ox : 0.01f * ox;
      oy = oy > 0.f ? oy : 0.01f * oy;
      oz = oz > 0.f ? oz : 0.01f * oz;
      ow = ow > 0.f ? ow : 0.01f * ow;
      p[i] = ox * w2.x + oy * w2.y + oz * w2.z + ow * w2.w;
    }
#pragma unroll
    for (int d = 1; d < 32; d <<= 1) {
#pragma unroll
      for (int i = 0; i < 4; ++i) p[i] += __shfl_xor(p[i], d, 32);
    }
    if ((tid & 31) == 0) {
      float rb = rb2[0];
#pragma unroll
      for (int i = 0; i < 4; ++i) {
        int r = rowBase + r0 + i;
        if (r < n) out1[r] = p[i] + rb;
      }
    }
    return;
  }

#pragma unroll
  for (int i = 0; i < 4; ++i) {
    int r = rowBase + r0 + i;
    if (r < n) {
      float4 o;
      o.x = acc[i][0] + bv.x; o.y = acc[i][1] + bv.y;
      o.z = acc[i][2] + bv.z; o.w = acc[i][3] + bv.w;
      o.x = o.x > 0.f ? o.x : 0.01f * o.x;
      o.y = o.y > 0.f ? o.y : 0.01f * o.y;
      o.z = o.z > 0.f ? o.z : 0.01f * o.z;
      o.w = o.w > 0.f ? o.w : 0.01f * o.w;
      *(float4*)&out[(size_t)r * HDIM + f0] = o;
    }
  }
}

// ---------------- aggregation (pull, CSR): one wave per node, bf16 table ----
// Row = 256B bf16; lane reads ushort2 (2 feats). Depth-8 pipeline keeps
// ~2KB/wave in flight. Accumulate fp32; out fp32 + bias + relu.
__global__ __launch_bounds__(256) void aggregate_kernel(const unsigned short* __restrict__ t,
                                                        const int* __restrict__ off,
                                                        const int2* __restrict__ recs,
                                                        const float* __restrict__ dinv,
                                                        const float* __restrict__ bias,
                                                        float* __restrict__ out, int n) {
  int node = (blockIdx.x * blockDim.x + threadIdx.x) >> 6;
  int lane = threadIdx.x & 63;
  if (node >= n) return;
  const ushort2* tf = (const ushort2*)t + lane;  // row r at tf[r*64]
  float di = dinv[node];
  float self = di * di;
  ushort2 v = tf[(size_t)node * 64];
  float ax = self * bf16tof(v.x), ay = self * bf16tof(v.y);
  int e0 = off[node], e1 = off[node + 1];
  int e = e0;
  for (; e + 8 <= e1; e += 8) {
    int2 r[8];
    ushort2 u[8];
#pragma unroll
    for (int j = 0; j < 8; ++j) r[j] = recs[e + j];
#pragma unroll
    for (int j = 0; j < 8; ++j) u[j] = tf[(size_t)r[j].x * 64];
#pragma unroll
    for (int j = 0; j < 8; ++j) {
      float w = __int_as_float(r[j].y);
      ax += w * bf16tof(u[j].x);
      ay += w * bf16tof(u[j].y);
    }
  }
  for (; e < e1; ++e) {
    int2 r = recs[e];
    float w = __int_as_float(r.y);
    ushort2 u = tf[(size_t)r.x * 64];
    ax += w * bf16tof(u.x);
    ay += w * bf16tof(u.y);
  }
  const float2* bf = (const float2*)bias + lane;
  float2 b = *bf;
  ax = fmaxf(ax + b.x, 0.f);
  ay = fmaxf(ay + b.y, 0.f);
  float2 o; o.x = ax; o.y = ay;
  *((float2*)out + (size_t)node * 64 + lane) = o;
}

// ---------------- host ----------------

static inline size_t align256(size_t x) { return (x + 255) & ~(size_t)255; }

extern "C" void kernel_launch(void* const* d_in, const int* in_sizes, int n_in,
                              void* d_out, int out_size, void* d_ws, size_t ws_size,
                              hipStream_t stream) {
  const float* x   = (const float*)d_in[0];
  const int*   ei  = (const int*)d_in[1];
  const float* W0  = (const float*)d_in[2];
  const float* b0  = (const float*)d_in[3];
  const float* W1  = (const float*)d_in[4];
  const float* b1  = (const float*)d_in[5];
  const float* W2  = (const float*)d_in[6];
  const float* b2  = (const float*)d_in[7];
  const float* Rw0 = (const float*)d_in[8];
  const float* Rb0 = (const float*)d_in[9];
  const float* Rw1 = (const float*)d_in[10];
  const float* Rb1 = (const float*)d_in[11];
  const float* Rw2 = (const float*)d_in[12];
  const float* Rb2 = (const float*)d_in[13];
  float* out = (float*)d_out;

  int N = in_sizes[0] / 6;
  int E = in_sizes[1] / 2;
  int NB = (N + 255) / 256;

  char* p = (char*)d_ws;
  size_t o = 0;
  int* deg     = (int*)(p + o); o = align256(o + (size_t)N * 4);
  int* cursor  = (int*)(p + o); o = align256(o + (size_t)N * 4);
  int* off     = (int*)(p + o); o = align256(o + (size_t)(N + 1) * 4);
  float* dinv  = (float*)(p + o); o = align256(o + (size_t)N * 4);
  int* bsums   = (int*)(p + o); o = align256(o + (size_t)NB * 4);
  int* bscan   = (int*)(p + o); o = align256(o + (size_t)NB * 4);
  int2* recs   = (int2*)(p + o); o = align256(o + (size_t)E * 8);
  float* aggx  = (float*)(p + o); o = align256(o + (size_t)N * 6 * 4);
  float* A     = (float*)(p + o); o = align256(o + (size_t)N * HDIM * 4);
  float* B     = (float*)(p + o); o = align256(o + (size_t)N * HDIM * 4);
  unsigned short* B16 = (unsigned short*)B;  // bf16 message table aliases B
  (void)ws_size;

  // graph prep
  init_deg<<<(N + 255) / 256, 256, 0, stream>>>(deg, N);
  hist_kernel<<<(E + 255) / 256, 256, 0, stream>>>(ei, E, deg);
  dinv_kernel<<<(N + 255) / 256, 256, 0, stream>>>(deg, dinv, N);
  block_sums_kernel<<<NB, 256, 0, stream>>>(deg, bsums, N);
  scan_bsums_kernel<<<1, 256, 0, stream>>>(bsums, bscan, NB);
  write_off_kernel<<<NB, 256, 0, stream>>>(deg, bscan, off, cursor, N);
  fill_kernel<<<(E + 255) / 256, 256, 0, stream>>>(ei, E, dinv, cursor, recs);

  // layer 0: propagate in 6-dim, then 6->128 gemm + relu
  prop6_kernel<<<(N + 31) / 32, 256, 0, stream>>>(x, off, recs, dinv, aggx, N);
  gemm0_kernel<<<(N + 15) / 16, 256, 0, stream>>>(aggx, W0, b0, A, N);

  int gemmGrid = (N + 31) / 32;
  int aggGrid = (N + 3) / 4;

  // conv1: transform (bf16 table) -> aggregate
  gemm128_kernel<0><<<gemmGrid, 256, 0, stream>>>(A, W1, nullptr, (float*)B16, N, nullptr, nullptr, nullptr);
  aggregate_kernel<<<aggGrid, 256, 0, stream>>>(B16, off, recs, dinv, b1, A, N);
  // conv2
  gemm128_kernel<0><<<gemmGrid, 256, 0, stream>>>(A, W2, nullptr, (float*)B16, N, nullptr, nullptr, nullptr);
  aggregate_kernel<<<aggGrid, 256, 0, stream>>>(B16, off, recs, dinv, b2, A, N);
  // MLP head
  gemm128_kernel<2><<<gemmGrid, 256, 0, stream>>>(A, Rw0, Rb0, B, N, nullptr, nullptr, nullptr);
  gemm128_kernel<3><<<gemmGrid, 256, 0, stream>>>(B, Rw1, Rb1, A, N, Rw2, Rb2, out);
}

// Round 9
// 403.230 us; speedup vs baseline: 1.7193x; 1.1108x over previous
//
#include <hip/hip_runtime.h>

// GCN on MI355X. R9:
//  - recs shrunk to 4B (src only); w = dinv[s]*dinv[d] computed on the fly
//    (dinv[d] factored out of the reduction). Halves fill's scatter region.
//  - all four [n,128]x[128,128] GEMMs -> bf16 MFMA (16x16x32), weights
//    pre-fragmented into B-operand order; activations bf16 end-to-end.
// Pipeline: deg/hist -> dinv -> scan -> fill -> prop6 -> gemm0(bf16 out)
//   -> wprep -> [mgemm<0> -> aggregate]x2 -> mgemm<2> -> mgemm<3>(+dot)

#define HDIM 128

typedef __attribute__((ext_vector_type(8))) short bf16x8;
typedef __attribute__((ext_vector_type(4))) float f32x4;

__device__ inline unsigned short bf16rn(float f) {
  unsigned u = __float_as_uint(f);
  unsigned r = (u + 0x7FFFu + ((u >> 16) & 1u)) >> 16;
  return (unsigned short)r;
}
__device__ inline float bf16tof(unsigned short h) {
  return __uint_as_float(((unsigned)h) << 16);
}

// ---------------- graph preprocessing ----------------

__global__ void init_deg(int* deg, int n) {
  int i = blockIdx.x * blockDim.x + threadIdx.x;
  if (i < n) deg[i] = 1;  // self loop
}

__global__ void hist_kernel(const int* __restrict__ ei, int E, int* __restrict__ deg) {
  int e = blockIdx.x * blockDim.x + threadIdx.x;
  if (e < E) atomicAdd(&deg[ei[E + e]], 1);  // dst = ei[1][e]
}

__global__ void dinv_kernel(const int* __restrict__ deg, float* __restrict__ dinv, int n) {
  int i = blockIdx.x * blockDim.x + threadIdx.x;
  if (i < n) dinv[i] = rsqrtf((float)deg[i]);
}

// --- parallel exclusive scan of (deg[i]-1), 256 elems/block ---

__global__ __launch_bounds__(256) void block_sums_kernel(const int* __restrict__ deg,
                                                         int* __restrict__ bsums, int n) {
  int i = blockIdx.x * 256 + threadIdx.x;
  int v = (i < n) ? (deg[i] - 1) : 0;
#pragma unroll
  for (int d = 1; d < 64; d <<= 1) v += __shfl_xor(v, d, 64);
  __shared__ int ws[4];
  int lane = threadIdx.x & 63, wid = threadIdx.x >> 6;
  if (lane == 0) ws[wid] = v;
  __syncthreads();
  if (threadIdx.x == 0) bsums[blockIdx.x] = ws[0] + ws[1] + ws[2] + ws[3];
}

__global__ __launch_bounds__(256) void scan_bsums_kernel(const int* __restrict__ bsums,
                                                         int* __restrict__ bscan, int nb) {
  int tid = threadIdx.x, lane = tid & 63, wid = tid >> 6;
  int v = (tid < nb) ? bsums[tid] : 0;
  int inc = v;
#pragma unroll
  for (int d = 1; d < 64; d <<= 1) {
    int t = __shfl_up(inc, (unsigned)d, 64);
    if (lane >= d) inc += t;
  }
  __shared__ int ws[4];
  if (lane == 63) ws[wid] = inc;
  __syncthreads();
  int woff = 0;
  for (int w = 0; w < wid; ++w) woff += ws[w];
  inc += woff;
  if (tid < nb) bscan[tid] = inc - v;
}

__global__ __launch_bounds__(256) void write_off_kernel(const int* __restrict__ deg,
                                                        const int* __restrict__ bscan,
                                                        int* __restrict__ off,
                                                        int* __restrict__ cursor, int n) {
  int i = blockIdx.x * 256 + threadIdx.x;
  int v = (i < n) ? (deg[i] - 1) : 0;
  int lane = threadIdx.x & 63, wid = threadIdx.x >> 6;
  int inc = v;
#pragma unroll
  for (int d = 1; d < 64; d <<= 1) {
    int t = __shfl_up(inc, (unsigned)d, 64);
    if (lane >= d) inc += t;
  }
  __shared__ int ws[4];
  if (lane == 63) ws[wid] = inc;
  __syncthreads();
  int woff = 0;
  for (int w = 0; w < wid; ++w) woff += ws[w];
  inc += woff;
  int base = bscan[blockIdx.x];
  if (i < n) {
    int ex = base + inc - v;
    off[i] = ex;
    cursor[i] = ex;
    if (i == n - 1) off[n] = base + inc;
  }
}

// 4B record per edge: src only (w computed on the fly by consumers)
__global__ void fill_kernel(const int* __restrict__ ei, int E,
                            int* __restrict__ cursor, int* __restrict__ recs) {
  int e = blockIdx.x * blockDim.x + threadIdx.x;
  if (e >= E) return;
  int s = ei[e], d = ei[E + e];
  int pos = atomicAdd(&cursor[d], 1);
  recs[pos] = s;
}

// ---------------- layer 0: propagate 6-dim features ----------------
__global__ void prop6_kernel(const float* __restrict__ x, const int* __restrict__ off,
                             const int* __restrict__ recs,
                             const float* __restrict__ dinv, float* __restrict__ aggx, int n) {
  int g = (blockIdx.x * blockDim.x + threadIdx.x) >> 3;
  int l = threadIdx.x & 7;
  if (g >= n) return;
  float di = dinv[g];
  float acc = 0.f;
  if (l < 6) acc = di * x[g * 6 + l];
  int e0 = off[g], e1 = off[g + 1];
  int e = e0;
  for (; e + 4 <= e1; e += 4) {
    int s0 = recs[e], s1 = recs[e + 1], s2 = recs[e + 2], s3 = recs[e + 3];
    float w0 = dinv[s0], w1 = dinv[s1], w2 = dinv[s2], w3 = dinv[s3];
    float u0 = 0.f, u1 = 0.f, u2 = 0.f, u3 = 0.f;
    if (l < 6) {
      u0 = x[s0 * 6 + l]; u1 = x[s1 * 6 + l];
      u2 = x[s2 * 6 + l]; u3 = x[s3 * 6 + l];
    }
    acc += w0 * u0 + w1 * u1 + w2 * u2 + w3 * u3;
  }
  for (; e < e1; ++e) {
    int s = recs[e];
    if (l < 6) acc += dinv[s] * x[s * 6 + l];
  }
  if (l < 6) aggx[g * 6 + l] = di * acc;
}

// h0 = relu(aggx @ W0 + b0): [n,6]x[6,128] -> bf16. 16 nodes per 256-block.
__global__ __launch_bounds__(256) void gemm0_kernel(const float* __restrict__ aggx,
                                                    const float* __restrict__ W0,
                                                    const float* __restrict__ b0,
                                                    unsigned short* __restrict__ out, int n) {
  __shared__ float Ws[6 * 128];
  __shared__ float bs[128];
  for (int i = threadIdx.x; i < 6 * 128; i += 256) Ws[i] = W0[i];
  if (threadIdx.x < 128) bs[threadIdx.x] = b0[threadIdx.x];
  __syncthreads();
  int f = threadIdx.x & 127;
  int h = threadIdx.x >> 7;  // 0 or 1
  int base = blockIdx.x * 16;
#pragma unroll
  for (int j = 0; j < 8; ++j) {
    int nd = base + h * 8 + j;
    if (nd < n) {
      float acc = bs[f];
#pragma unroll
      for (int k = 0; k < 6; ++k) acc += aggx[nd * 6 + k] * Ws[k * 128 + f];
      out[(size_t)nd * HDIM + f] = bf16rn(fmaxf(acc, 0.f));
    }
  }
}

// ---------------- weight prep: fp32 W[128][128] -> bf16 fragment order -----
// Frag layout per weight (32KB): chunk c=(ft*4+kk)*64+l holds 8 bf16:
//   elem j = W[kk*32 + (l>>4)*8 + j][ft*16 + (l&15)]
__global__ __launch_bounds__(256) void wprep_kernel(const float* __restrict__ w1,
                                                    const float* __restrict__ w2,
                                                    const float* __restrict__ rw0,
                                                    const float* __restrict__ rw1,
                                                    unsigned short* __restrict__ wtf) {
  int widx = blockIdx.y;
  const float* W = (widx == 0) ? w1 : (widx == 1) ? w2 : (widx == 2) ? rw0 : rw1;
  int c = blockIdx.x * 256 + threadIdx.x;  // 0..2047
  int l = c & 63, kk = (c >> 6) & 3, ft = c >> 8;
  int f = ft * 16 + (l & 15);
  int k0 = kk * 32 + ((l >> 4) << 3);
  unsigned short v[8];
#pragma unroll
  for (int j = 0; j < 8; ++j) v[j] = bf16rn(W[(size_t)(k0 + j) * 128 + f]);
  uint4 pk;
  pk.x = (unsigned)v[0] | ((unsigned)v[1] << 16);
  pk.y = (unsigned)v[2] | ((unsigned)v[3] << 16);
  pk.z = (unsigned)v[4] | ((unsigned)v[5] << 16);
  pk.w = (unsigned)v[6] | ((unsigned)v[7] << 16);
  *(uint4*)&wtf[((size_t)widx * 16384) + (size_t)c * 8] = pk;
}

// ---------------- MFMA GEMM: [n,128](bf16) @ W[128,128] ----------------
// Block: 256 thr / 4 waves, 64-row tile. LDS: A 16KB (swizzled) + W 32KB (frag).
// ACT: 0 = raw -> bf16 out; 2 = bias+leaky -> bf16 out;
//      3 = bias+leaky, dot rw2, +rb2 -> fp32 out1[n]
template <int ACT>
__global__ __launch_bounds__(256) void mgemm_kernel(const unsigned short* __restrict__ in,
                                                    const unsigned short* __restrict__ wtf,
                                                    const float* __restrict__ bias,
                                                    unsigned short* __restrict__ out, int n,
                                                    const float* __restrict__ rw2,
                                                    const float* __restrict__ rb2,
                                                    float* __restrict__ out1) {
  __shared__ unsigned short Alds[8192];   // 16KB: [k8][row^(k8&7)] 16B units
  __shared__ unsigned short Wlds[16384];  // 32KB fragment-ordered
  int tid = threadIdx.x;
  int rowBase = blockIdx.x * 64;
  {
    const uint4* src = (const uint4*)wtf;
    uint4* dst = (uint4*)Wlds;
#pragma unroll
    for (int c = 0; c < 8; ++c) dst[c * 256 + tid] = src[c * 256 + tid];
  }
  {
    int k8 = tid & 15, tr = tid >> 4;
#pragma unroll
    for (int c = 0; c < 4; ++c) {
      int row = tr + c * 16;
      int gr = rowBase + row;
      uint4 v = make_uint4(0u, 0u, 0u, 0u);
      if (gr < n) v = *(const uint4*)&in[(size_t)gr * HDIM + k8 * 8];
      int srow = row ^ (k8 & 7);
      *(uint4*)&Alds[k8 * 512 + srow * 8] = v;
    }
  }
  __syncthreads();
  int wv = tid >> 6, lane = tid & 63;
  int l16 = lane >> 4, fcol = lane & 15;
  int lrow = wv * 16 + fcol;  // A-frag row (m = lane&15)
  bf16x8 af[4];
#pragma unroll
  for (int kk = 0; kk < 4; ++kk) {
    int k8 = kk * 4 + l16;
    int srow = lrow ^ (k8 & 7);
    af[kk] = *(const bf16x8*)&Alds[k8 * 512 + srow * 8];
  }
  f32x4 acc[8];
#pragma unroll
  for (int ft = 0; ft < 8; ++ft) acc[ft] = (f32x4)(0.f);
#pragma unroll
  for (int ft = 0; ft < 8; ++ft) {
#pragma unroll
    for (int kk = 0; kk < 4; ++kk) {
      bf16x8 bfr = *(const bf16x8*)&Wlds[(((ft * 4 + kk) * 64) + lane) * 8];
      acc[ft] = __builtin_amdgcn_mfma_f32_16x16x32_bf16(af[kk], bfr, acc[ft], 0, 0, 0);
    }
  }
  int orow0 = rowBase + wv * 16 + l16 * 4;  // D: col=lane&15, row=(lane>>4)*4+reg

  if (ACT == 3) {
    float p[4] = {0.f, 0.f, 0.f, 0.f};
#pragma unroll
    for (int ft = 0; ft < 8; ++ft) {
      int f = ft * 16 + fcol;
      float bb = bias[f], ww = rw2[f];
#pragma unroll
      for (int r = 0; r < 4; ++r) {
        float v = acc[ft][r] + bb;
        v = v > 0.f ? v : 0.01f * v;
        p[r] += v * ww;
      }
    }
#pragma unroll
    for (int d = 1; d < 16; d <<= 1) {
#pragma unroll
      for (int r = 0; r < 4; ++r) p[r] += __shfl_xor(p[r], d, 64);
    }
    if (fcol == 0) {
      float rb = rb2[0];
#pragma unroll
      for (int r = 0; r < 4; ++r) {
        int row = orow0 + r;
        if (row < n) out1[row] = p[r] + rb;
      }
    }
    return;
  }

#pragma unroll
  for (int ft = 0; ft < 8; ++ft) {
    int f = ft * 16 + fcol;
    float bb = (ACT == 2) ? bias[f] : 0.f;
#pragma unroll
    for (int r = 0; r < 4; ++r) {
      int row = orow0 + r;
      if (row < n) {
        float v = acc[ft][r];
        if (ACT == 2) {
          v += bb;
          v = v > 0.f ? v : 0.01f * v;
        }
        out[(size_t)row * HDIM + f] = bf16rn(v);
      }
    }
  }
}

// ---------------- aggregation (pull, CSR): one wave per node, bf16 ----------
// out = relu( dinv[d]*(sum dinv[s]*t[s] + dinv[d]*t[d]) + b ) -> bf16
__global__ __launch_bounds__(256) void aggregate_kernel(const unsigned short* __restrict__ t,
                                                        const int* __restrict__ off,
                                                        const int* __restrict__ recs,
                                                        const float* __restrict__ dinv,
                                                        const float* __restrict__ bias,
                                                        unsigned short* __restrict__ out, int n) {
  int node = (blockIdx.x * blockDim.x + threadIdx.x) >> 6;
  int lane = threadIdx.x & 63;
  if (node >= n) return;
  const ushort2* tf = (const ushort2*)t + lane;  // row r at tf[r*64]
  float di = dinv[node];
  ushort2 v = tf[(size_t)node * 64];
  float ax = di * bf16tof(v.x), ay = di * bf16tof(v.y);
  int e0 = off[node], e1 = off[node + 1];
  int e = e0;
  for (; e + 8 <= e1; e += 8) {
    int s[8];
    ushort2 u[8];
    float w[8];
#pragma unroll
    for (int j = 0; j < 8; ++j) s[j] = recs[e + j];
#pragma unroll
    for (int j = 0; j < 8; ++j) u[j] = tf[(size_t)s[j] * 64];
#pragma unroll
    for (int j = 0; j < 8; ++j) w[j] = dinv[s[j]];
#pragma unroll
    for (int j = 0; j < 8; ++j) {
      ax += w[j] * bf16tof(u[j].x);
      ay += w[j] * bf16tof(u[j].y);
    }
  }
  for (; e < e1; ++e) {
    int s = recs[e];
    float w = dinv[s];
    ushort2 u = tf[(size_t)s * 64];
    ax += w * bf16tof(u.x);
    ay += w * bf16tof(u.y);
  }
  const float2* bf = (const float2*)bias + lane;
  float2 b = *bf;
  ax = fmaxf(di * ax + b.x, 0.f);
  ay = fmaxf(di * ay + b.y, 0.f);
  ushort2 o;
  o.x = bf16rn(ax);
  o.y = bf16rn(ay);
  *((ushort2*)out + (size_t)node * 64 + lane) = o;
}

// ---------------- host ----------------

static inline size_t align256(size_t x) { return (x + 255) & ~(size_t)255; }

extern "C" void kernel_launch(void* const* d_in, const int* in_sizes, int n_in,
                              void* d_out, int out_size, void* d_ws, size_t ws_size,
                              hipStream_t stream) {
  const float* x   = (const float*)d_in[0];
  const int*   ei  = (const int*)d_in[1];
  const float* W0  = (const float*)d_in[2];
  const float* b0  = (const float*)d_in[3];
  const float* W1  = (const float*)d_in[4];
  const float* b1  = (const float*)d_in[5];
  const float* W2  = (const float*)d_in[6];
  const float* b2  = (const float*)d_in[7];
  const float* Rw0 = (const float*)d_in[8];
  const float* Rb0 = (const float*)d_in[9];
  const float* Rw1 = (const float*)d_in[10];
  const float* Rb1 = (const float*)d_in[11];
  const float* Rw2 = (const float*)d_in[12];
  const float* Rb2 = (const float*)d_in[13];
  float* out = (float*)d_out;

  int N = in_sizes[0] / 6;
  int E = in_sizes[1] / 2;
  int NB = (N + 255) / 256;

  char* p = (char*)d_ws;
  size_t o = 0;
  int* deg     = (int*)(p + o); o = align256(o + (size_t)N * 4);
  int* cursor  = (int*)(p + o); o = align256(o + (size_t)N * 4);
  int* off     = (int*)(p + o); o = align256(o + (size_t)(N + 1) * 4);
  float* dinv  = (float*)(p + o); o = align256(o + (size_t)N * 4);
  int* bsums   = (int*)(p + o); o = align256(o + (size_t)NB * 4);
  int* bscan   = (int*)(p + o); o = align256(o + (size_t)NB * 4);
  int* recs    = (int*)(p + o); o = align256(o + (size_t)E * 4);
  float* aggx  = (float*)(p + o); o = align256(o + (size_t)N * 6 * 4);
  unsigned short* Wtf = (unsigned short*)(p + o); o = align256(o + (size_t)4 * 16384 * 2);
  unsigned short* H0  = (unsigned short*)(p + o); o = align256(o + (size_t)N * HDIM * 2);
  unsigned short* H1  = (unsigned short*)(p + o); o = align256(o + (size_t)N * HDIM * 2);
  (void)ws_size;

  // graph prep
  init_deg<<<(N + 255) / 256, 256, 0, stream>>>(deg, N);
  hist_kernel<<<(E + 255) / 256, 256, 0, stream>>>(ei, E, deg);
  dinv_kernel<<<(N + 255) / 256, 256, 0, stream>>>(deg, dinv, N);
  block_sums_kernel<<<NB, 256, 0, stream>>>(deg, bsums, N);
  scan_bsums_kernel<<<1, 256, 0, stream>>>(bsums, bscan, NB);
  write_off_kernel<<<NB, 256, 0, stream>>>(deg, bscan, off, cursor, N);
  fill_kernel<<<(E + 255) / 256, 256, 0, stream>>>(ei, E, cursor, recs);

  // weight prep (independent of graph work)
  {
    dim3 g(8, 4);
    wprep_kernel<<<g, 256, 0, stream>>>(W1, W2, Rw0, Rw1, Wtf);
  }

  // layer 0: propagate in 6-dim, then 6->128 gemm + relu -> bf16
  prop6_kernel<<<(N + 31) / 32, 256, 0, stream>>>(x, off, recs, dinv, aggx, N);
  gemm0_kernel<<<(N + 15) / 16, 256, 0, stream>>>(aggx, W0, b0, H0, N);

  int mGrid = (N + 63) / 64;
  int aggGrid = (N + 3) / 4;

  // conv1: transform (bf16 MFMA) -> aggregate
  mgemm_kernel<0><<<mGrid, 256, 0, stream>>>(H0, Wtf + 0 * 16384, nullptr, H1, N, nullptr, nullptr, nullptr);
  aggregate_kernel<<<aggGrid, 256, 0, stream>>>(H1, off, recs, dinv, b1, H0, N);
  // conv2
  mgemm_kernel<0><<<mGrid, 256, 0, stream>>>(H0, Wtf + 1 * 16384, nullptr, H1, N, nullptr, nullptr, nullptr);
  aggregate_kernel<<<aggGrid, 256, 0, stream>>>(H1, off, recs, dinv, b2, H0, N);
  // MLP head
  mgemm_kernel<2><<<mGrid, 256, 0, stream>>>(H0, Wtf + 2 * 16384, Rb0, H1, N, nullptr, nullptr, nullptr);
  mgemm_kernel<3><<<mGrid, 256, 0, stream>>>(H1, Wtf + 3 * 16384, Rb1, nullptr, N, Rw2, Rb2, out);
}